// Round 7
// baseline (164.887 us; speedup 1.0000x reference)
//
#include <hip/hip_runtime.h>

// Transposed flash attention, f16 MFMA (16x16x32), no-max softmax, split-K=2.
// R16 (resubmit R17: round-6 bench was a container-acquisition infra failure,
// no kernel verdict). Theory: the limiter is the per-wave serial chain
// QK->exp->PV (~1200cyc/h-block; measured 1560/2-wave pair -> pipes alternate
// idle). R15's counted-vmcnt gate bought only 1.5% (drain was not the stall);
// occupancy (R11/R12) and no-barrier (R13/R14) also falsified. Fix = T15
// att[2] h-block software pipeline: TWO score states (scA/scB, static names,
// rule #20); exp(prev) runs on VALU while next h-block's 16 QK MFMAs issue
// on the matrix pipe, carried ACROSS the tile gate so no exp is
// serial-exposed:
//   QK(t,h1)->scB || exp(scA); PV(t,h0); GATE; ASYNC(t+3);
//   QK(t+1,h0)->scA || exp(scB); PV(t,h1)
// 4-ring WAR-safe: stage target (t+3)&3=(t-1)&3 last read pre-gate (ds_reads
// retire before consuming MFMAs -> before barrier). vmcnt(4) at every gate
// (8 outstanding). setprio DROPPED (would fence the MFMA||VALU interleave).
// Numerics BIT-IDENTICAL to R10/R15 (same ops, same order). Peak live
// ~200-220 VGPR < 256 cap of launch_bounds(256,2) (R9 disaster was a 128
// cap). Failure reads: flat+VALUBusy flat -> force interleave via
// sched_group_barrier next; scratch>0 -> shrink carry granularity.

#define NBATCH 16
#define SEQ    4096
#define DIM    64
#define BQ     256
#define BK     64
#define NKT    (SEQ / BK)      // 64
#define KHALF  (NKT / 2)       // 32 tiles per key-half
#define OELEMS (NBATCH * SEQ * DIM)   // 4194304
#define NROWS  (NBATCH * SEQ)         // 65536
#define NTILES (NBATCH * NKT)         // 1024
#define TILEH  4096                   // halfs per 64x64 tile image (8 KB)

#define QSCALE 0.180336879f   // 0.125 * log2(e)

typedef _Float16 half2_t __attribute__((ext_vector_type(2)));
typedef _Float16 half4_t __attribute__((ext_vector_type(4)));
typedef _Float16 half8_t __attribute__((ext_vector_type(8)));
typedef float    floatx4 __attribute__((ext_vector_type(4)));

__device__ inline float fast_exp2(float x) {
#if __has_builtin(__builtin_amdgcn_exp2f)
  return __builtin_amdgcn_exp2f(x);
#else
  return exp2f(x);
#endif
}
__device__ inline float fast_rcp(float x) {
#if __has_builtin(__builtin_amdgcn_rcpf)
  return __builtin_amdgcn_rcpf(x);
#else
  return 1.0f / x;
#endif
}

// swizzled offset in halfs for element (row, col) of a 64x64 half tile
__device__ inline int swz(int row, int col) {
  return row * 64 + ((((col >> 3) ^ ((row >> 1) & 7)) << 3) | (col & 7));
}

// async 16B global->LDS copy: lds dest is wave-uniform; HW adds lane*16
__device__ inline void async16(const void* g, void* l) {
  __builtin_amdgcn_global_load_lds(
      (const __attribute__((address_space(1))) void*)g,
      (__attribute__((address_space(3))) void*)l, 16, 0, 0);
}

// ---------------- prepack: K,V f32 -> per-tile f16 LDS images ----------------
__global__ __launch_bounds__(256, 2)
void prepack_kv(const float* __restrict__ Kg, const float* __restrict__ Vg,
                _Float16* __restrict__ Kh, _Float16* __restrict__ Vh)
{
  __shared__ __align__(16) _Float16 sKi[TILEH];
  __shared__ __align__(16) _Float16 sVi[TILEH];
  const int tid = threadIdx.x;
  const int t16 = tid & 15;
  const int kg  = tid >> 4;
  const int bt  = blockIdx.x;                 // b*64 + kt
  const float* Kt_ = Kg + (size_t)bt * BK * DIM;
  const float* Vt_ = Vg + (size_t)bt * BK * DIM;

  floatx4 kbuf[4], vbuf[4];
  #pragma unroll
  for (int i = 0; i < 4; ++i) {
    const int key = kg + 16 * i;
    kbuf[i] = *(const floatx4*)(Kt_ + key * DIM + t16 * 4);
    vbuf[i] = *(const floatx4*)(Vt_ + key * DIM + t16 * 4);
  }
  #pragma unroll
  for (int i = 0; i < 4; ++i) {               // K: [key][dim] swizzled
    const int key = kg + 16 * i;
    half4_t h;
    #pragma unroll
    for (int j = 0; j < 4; ++j) h[j] = (_Float16)kbuf[i][j];
    *(half4_t*)&sKi[swz(key, t16 * 4)] = h;
  }
  {                                           // V: [dim][slot] swizzled
    const int vbase = (kg >> 2) * 8 + (kg & 3) * 2;
    #pragma unroll
    for (int e = 0; e < 4; ++e) {
      const int dim = t16 * 4 + e;
      half2_t h0; h0[0] = (_Float16)vbuf[0][e]; h0[1] = (_Float16)vbuf[1][e];
      half2_t h1; h1[0] = (_Float16)vbuf[2][e]; h1[1] = (_Float16)vbuf[3][e];
      *(half2_t*)&sVi[swz(dim, vbase)]      = h0;
      *(half2_t*)&sVi[swz(dim, vbase + 32)] = h1;
    }
  }
  __syncthreads();
  half8_t* Ko = (half8_t*)(Kh + (size_t)bt * TILEH);
  half8_t* Vo = (half8_t*)(Vh + (size_t)bt * TILEH);
  const half8_t* Ks = (const half8_t*)sKi;
  const half8_t* Vs = (const half8_t*)sVi;
  Ko[tid] = Ks[tid]; Ko[tid + 256] = Ks[tid + 256];
  Vo[tid] = Vs[tid]; Vo[tid + 256] = Vs[tid + 256];
}

// ---------------- main kernel ----------------
__global__ __launch_bounds__(256, 2)
void attn_f16_flash(const float* __restrict__ Qg, const _Float16* __restrict__ Kh,
                    const _Float16* __restrict__ Vh, float* __restrict__ O0g,
                    float* __restrict__ O1g, float* __restrict__ lsg)
{
  __shared__ __align__(16) _Float16 sT[4][2 * TILEH];  // ring: [buf][ K | V ]

  const int tid  = threadIdx.x;
  const int wave = tid >> 6;
  const int lane = tid & 63;
  const int l16  = lane & 15;
  const int quad = lane >> 4;
  const int hK   = (l16 >> 1) & 7;

  // XCD-clustered decode (bijective over 512 blocks): XCD x = bid&7 gets
  // batches {x, x+8} only -> 2MB K/V image working set per 4MB XCD L2.
  const int bid  = blockIdx.x;
  const int x    = bid & 7;
  const int r    = bid >> 3;                // 0..63
  const int b    = x + ((r & 1) << 3);
  const int qt   = (r >> 1) & 15;
  const int half = (r >> 5) & 1;
  const int q0   = qt * BQ + wave * 64;
  const int kt0  = half * KHALF;

  const float* Qb = Qg + ((size_t)b * SEQ + q0) * DIM;
  float*       Ob = (half ? O1g : O0g) + ((size_t)b * SEQ + q0) * DIM;
  float*       Ls = lsg + (size_t)half * NROWS + b * SEQ + q0;

  // ---- Q fragments (B-operand of S^T = K*Q^T), pre-scaled ----
  half8_t qf[4][2];
  #pragma unroll
  for (int s = 0; s < 4; ++s)
    #pragma unroll
    for (int c = 0; c < 2; ++c) {
      const floatx4 f0 = *(const floatx4*)(Qb + (s * 16 + l16) * DIM + c * 32 + quad * 8);
      const floatx4 f1 = *(const floatx4*)(Qb + (s * 16 + l16) * DIM + c * 32 + quad * 8 + 4);
      half8_t h;
      #pragma unroll
      for (int j = 0; j < 4; ++j) h[j] = (_Float16)(f0[j] * QSCALE);
      #pragma unroll
      for (int j = 0; j < 4; ++j) h[4 + j] = (_Float16)(f1[j] * QSCALE);
      qf[s][c] = h;
    }

  floatx4 oacc2[4][4];   // [dim-tile n][q-slab s]
  float   lsum2[4];
  #pragma unroll
  for (int n = 0; n < 4; ++n)
    #pragma unroll
    for (int s = 0; s < 4; ++s) oacc2[n][s] = (floatx4){0.f, 0.f, 0.f, 0.f};
  #pragma unroll
  for (int s = 0; s < 4; ++s) lsum2[s] = 0.f;

  // ---- async staging: 4 x 16B-per-lane copies per wave per tile ----
  #define ASYNC(KT, BUF)                                                       \
    do {                                                                       \
      const char* gk = (const char*)(Kh + ((size_t)b * NKT + (KT)) * TILEH)    \
                       + wave * 2048;                                          \
      const char* gv = (const char*)(Vh + ((size_t)b * NKT + (KT)) * TILEH)    \
                       + wave * 2048;                                          \
      char* lk = (char*)(&sT[BUF][0])     + wave * 2048;                       \
      char* lv = (char*)(&sT[BUF][TILEH]) + wave * 2048;                       \
      async16(gk + lane * 16,        lk);                                      \
      async16(gk + 1024 + lane * 16, lk + 1024);                               \
      async16(gv + lane * 16,        lv);                                      \
      async16(gv + 1024 + lane * 16, lv + 1024);                               \
    } while (0)

  // ---- QK^T of h-block H from ring buffer BUF into scX ----
  #define QKH(scX, BUF, H)                                                     \
    do {                                                                       \
      const _Float16* SKB = &sT[BUF][0];                                       \
      _Pragma("unroll")                                                        \
      for (int k2 = 0; k2 < 2; ++k2)                                           \
        _Pragma("unroll")                                                      \
        for (int s = 0; s < 4; ++s) scX[k2][s] = (floatx4){0.f, 0.f, 0.f, 0.f};\
      _Pragma("unroll")                                                        \
      for (int k2 = 0; k2 < 2; ++k2) {                                         \
        const int nk = (H) * 2 + k2;                                           \
        _Pragma("unroll")                                                      \
        for (int c = 0; c < 2; ++c) {                                          \
          half8_t kf = *(const half8_t*)&SKB[(nk * 16 + l16) * 64 +            \
                                             (((c * 4 + quad) ^ hK) << 3)];    \
          _Pragma("unroll")                                                    \
          for (int s = 0; s < 4; ++s)                                          \
            scX[k2][s] = __builtin_amdgcn_mfma_f32_16x16x32_f16(               \
                kf, qf[s][c], scX[k2][s], 0, 0, 0);                            \
        }                                                                      \
      }                                                                        \
    } while (0)

  // ---- softmax exp of scX -> bfrX (+ lsum) ----
  #define EXPH(scX, bfrX)                                                      \
    do {                                                                       \
      _Pragma("unroll")                                                        \
      for (int s = 0; s < 4; ++s) {                                            \
        half8_t bf;                                                            \
        _Pragma("unroll")                                                      \
        for (int j = 0; j < 8; ++j) {                                          \
          float p = fast_exp2(scX[j & 1][s][j >> 1]);                          \
          lsum2[s] += p;                                                       \
          bf[j] = (_Float16)p;                                                 \
        }                                                                      \
        bfrX[s] = bf;                                                          \
      }                                                                        \
    } while (0)

  // ---- PV accumulate of h-block H from ring buffer BUF with bfrX ----
  #define PVH(bfrX, BUF, H)                                                    \
    do {                                                                       \
      const _Float16* SVB = &sT[BUF][TILEH];                                   \
      _Pragma("unroll")                                                        \
      for (int n = 0; n < 4; ++n) {                                            \
        half8_t vf = *(const half8_t*)&SVB[(n * 16 + l16) * 64 +               \
                                           ((((H) * 4 + quad) ^ hK) << 3)];    \
        _Pragma("unroll")                                                      \
        for (int s = 0; s < 4; ++s)                                            \
          oacc2[n][s] = __builtin_amdgcn_mfma_f32_16x16x32_f16(                \
              vf, bfrX[s], oacc2[n][s], 0, 0, 0);                              \
      }                                                                        \
    } while (0)

  // counted-vmcnt phase gate: my loads older than newest N done + barrier
  // => all waves' data for the gated tile landed. Loads stay in flight.
  #define GATE(N)                                                              \
    do {                                                                       \
      asm volatile("s_waitcnt vmcnt(" #N ")" ::: "memory");                    \
      __builtin_amdgcn_s_barrier();                                            \
      __builtin_amdgcn_sched_barrier(0);                                       \
    } while (0)

  floatx4 scA[2][4], scB[2][4];
  half8_t bfrA[4], bfrB[4];

  // ---------- prologue ----------
  ASYNC(kt0 + 0, 0);
  ASYNC(kt0 + 1, 1);
  GATE(4);                         // tile 0 landed; tile 1 in flight
  ASYNC(kt0 + 2, 2);
  QKH(scA, 0, 0);

  // ---------- pipelined main loop (t = 0 .. KHALF-3) ----------
  // At each GATE: outstanding = tiles t+1, t+2 (8 loads) -> vmcnt(4)
  // guarantees tile t+1; tile t+2 stays in flight across the barrier.
  #pragma unroll 1
  for (int t = 0; t < KHALF - 2; ++t) {
    const int cb = t & 3;
    QKH(scB, cb, 1);               // matrix: tile t, h1
    EXPH(scA, bfrA);               // VALU: overlaps QKH above
    PVH(bfrA, cb, 0);              // matrix: tile t, h0
    GATE(4);
    if (t + 3 < KHALF) ASYNC(kt0 + t + 3, (t + 3) & 3);
    QKH(scA, (t + 1) & 3, 0);      // matrix: tile t+1, h0 (fresh buffer)
    EXPH(scB, bfrB);               // VALU: overlaps QKH above
    PVH(bfrB, cb, 1);              // matrix: tile t, h1 (old buffer -- WAR
                                   // safe: stage target (t+3)&3 != t&3)
  }

  // ---------- epilogue: t = KHALF-2 then KHALF-1 ----------
  {
    const int cb = (KHALF - 2) & 3;
    QKH(scB, cb, 1);
    EXPH(scA, bfrA);
    PVH(bfrA, cb, 0);
    GATE(0);                       // only tile KHALF-1 outstanding: drain it
    QKH(scA, (KHALF - 1) & 3, 0);
    EXPH(scB, bfrB);
    PVH(bfrB, cb, 1);
  }
  {
    const int cb = (KHALF - 1) & 3;
    QKH(scB, cb, 1);
    EXPH(scA, bfrA);
    PVH(bfrA, cb, 0);
    EXPH(scB, bfrB);
    PVH(bfrB, cb, 1);
  }

  // ---------- epilogue: UNNORMALIZED partial O^T + row sums ----------
  #pragma unroll
  for (int s = 0; s < 4; ++s) {
    float v = lsum2[s];
    v += __shfl_xor(v, 16);
    v += __shfl_xor(v, 32);
    if (lane < 16) Ls[s * 16 + l16] = v;
  }
  #pragma unroll
  for (int s = 0; s < 4; ++s)
    #pragma unroll
    for (int n = 0; n < 4; ++n)
      *(floatx4*)&Ob[(s * 16 + l16) * DIM + n * 16 + quad * 4] = oacc2[n][s];

  #undef ASYNC
  #undef QKH
  #undef EXPH
  #undef PVH
  #undef GATE
}

// O = (O0 + O1) / (l0 + l1); O0 in d_out (in-place), O1/l0/l1 in ws.
__global__ __launch_bounds__(256)
void attn_combine(float* __restrict__ O, const float* __restrict__ O1,
                  const float* __restrict__ lsg)
{
  const int i = blockIdx.x * 256 + threadIdx.x;   // float4 index
  const int row = i >> 4;
  const float inv = fast_rcp(lsg[row] + lsg[NROWS + row]);
  const float4 a  = ((const float4*)O)[i];
  const float4 bb = ((const float4*)O1)[i];
  float4 r;
  r.x = (a.x + bb.x) * inv;
  r.y = (a.y + bb.y) * inv;
  r.z = (a.z + bb.z) * inv;
  r.w = (a.w + bb.w) * inv;
  ((float4*)O)[i] = r;
}

extern "C" void kernel_launch(void* const* d_in, const int* in_sizes, int n_in,
                              void* d_out, int out_size, void* d_ws, size_t ws_size,
                              hipStream_t stream) {
  const float* Q = (const float*)d_in[0];
  const float* K = (const float*)d_in[1];
  const float* V = (const float*)d_in[2];
  float* O  = (float*)d_out;
  (void)in_sizes; (void)n_in; (void)out_size; (void)ws_size;

  // ws layout (floats): O1 [OELEMS] | Ls [2*NROWS] | Kh,Vh images (f16)
  float*     O1 = (float*)d_ws;
  float*     Ls = O1 + OELEMS;
  _Float16*  Kh = (_Float16*)(Ls + 2 * NROWS);
  _Float16*  Vh = Kh + (size_t)NTILES * TILEH;
  // total: (4.19M + 0.13M)*4B + 2*4.19M*2B = ~34.1 MB (fits: R9 proved >=51 MB)

  prepack_kv<<<dim3(NTILES), dim3(256), 0, stream>>>(K, V, Kh, Vh);
  attn_f16_flash<<<dim3(2 * NBATCH * (SEQ / BQ)), dim3(256), 0, stream>>>(
      Q, Kh, Vh, O, O1, Ls);
  attn_combine<<<dim3(OELEMS / 4 / 256), dim3(256), 0, stream>>>(O, O1, Ls);
}